// Round 7
// baseline (187.147 us; speedup 1.0000x reference)
//
#include <hip/hip_runtime.h>

typedef unsigned short u16;
typedef unsigned short u16x8 __attribute__((ext_vector_type(8)));
typedef unsigned short u16x4 __attribute__((ext_vector_type(4)));
typedef short s16x4 __attribute__((ext_vector_type(4)));
typedef __bf16 bf16x8_t __attribute__((ext_vector_type(8)));
typedef float floatx4 __attribute__((ext_vector_type(4)));

#define BATCH 2
#define S_LEN 2048
#define D_DIM 1024
#define NH    16
#define HD    64

__device__ __forceinline__ u16 f2b(float f) {   // RNE, finite only
  union { float f; unsigned int i; } c; c.f = f;
  const unsigned int i = c.i;
  return (u16)((i + 0x7FFFu + ((i >> 16) & 1u)) >> 16);
}
__device__ __forceinline__ unsigned int fbits(float f) {
  union { float f; unsigned int i; } c; c.f = f; return c.i;
}
__device__ __forceinline__ bf16x8_t asbf(u16x8 v) {
  union { u16x8 u; bf16x8_t b; } c; c.u = v; return c.b;
}
__device__ __forceinline__ s16x4 as4(uint2 v) {
  union { uint2 u; s16x4 s; } c; c.u = v; return c.s;
}
__device__ __forceinline__ s16x4 as4u(u16x4 v) {
  union { u16x4 u; s16x4 s; } c; c.u = v; return c.s;
}
__device__ __forceinline__ u16x8 cat44(u16x4 a, u16x4 b) {
  u16x8 r;
#pragma unroll
  for (int i = 0; i < 4; ++i) { r[i] = a[i]; r[4 + i] = b[i]; }
  return r;
}
__device__ __forceinline__ void load_lds16(const u16* g, u16* l) {
  __builtin_amdgcn_global_load_lds(
      (const __attribute__((address_space(1))) void*)g,
      (__attribute__((address_space(3))) void*)l, 16, 0, 0);
}

// Scratch in device globals, fully rewritten every call (graph-replay safe).
__device__ __attribute__((aligned(256))) u16 g_xb[(size_t)BATCH * S_LEN * D_DIM];   // 8 MB
__device__ __attribute__((aligned(256))) u16 g_wt[3u * D_DIM * D_DIM];              // 6 MB
// Q (pre-scaled by 0.125*log2e), K: fragment-blocked [bh][hd/4][s][4]
//   (value at ((hd>>2)*S_LEN + s)*4 + (hd&3))  -> qkv C-frag u16x4 stores are
//   contiguous; lanes (consecutive s) stride 8B = coalesced (the V fix, applied
//   to Q/K; V fix measured -11.2 us in round 2).
// V: fragment-blocked [bh][s/4][hd][4]  (value V(s,hd) at ((s>>2)*64+hd)*4+(s&3))
__device__ __attribute__((aligned(256))) u16 g_qkv[3u * BATCH * S_LEN * D_DIM];     // 25 MB

// ---------------------------------------------------------------------------
// Fused prep: blockIdx.y = 0..2 -> transpose+convert W[y]; y = 3 -> convert X.
// ---------------------------------------------------------------------------
__global__ __launch_bounds__(256) void prep(const float* __restrict__ X,
                                            const float* __restrict__ Wq,
                                            const float* __restrict__ Wk,
                                            const float* __restrict__ Wv) {
  const int tid = threadIdx.x;
  const int z = blockIdx.y;
  if (z == 3) {
#pragma unroll
    for (int c = 0; c < 8; ++c) {
      const size_t i = (((size_t)c * 256 + blockIdx.x) * 256 + tid) * 8;
      floatx4 a = *(const floatx4*)(X + i);
      floatx4 b = *(const floatx4*)(X + i + 4);
      u16x8 o;
#pragma unroll
      for (int j = 0; j < 4; ++j) { o[j] = f2b(a[j]); o[4 + j] = f2b(b[j]); }
      *(u16x8*)(g_xb + i) = o;
    }
    return;
  }
  __shared__ u16 t[64][65];
  const float* W = (z == 0) ? Wq : (z == 1) ? Wk : Wv;
  u16* Wt = g_wt + (size_t)z * D_DIM * D_DIM;
  const int k0 = (blockIdx.x & 15) * 64;
  const int n0 = (blockIdx.x >> 4) * 64;
  const int rr = tid >> 4;
  const int cc = (tid & 15) * 4;
#pragma unroll
  for (int i = 0; i < 4; ++i) {
    const int r = rr + i * 16;
    floatx4 v = *(const floatx4*)(W + (size_t)(k0 + r) * D_DIM + n0 + cc);
    t[r][cc] = f2b(v[0]); t[r][cc + 1] = f2b(v[1]);
    t[r][cc + 2] = f2b(v[2]); t[r][cc + 3] = f2b(v[3]);
  }
  __syncthreads();
#pragma unroll
  for (int i = 0; i < 4; ++i) {
    const int r = rr + i * 16;
    u16x4 v;
    v[0] = t[cc][r]; v[1] = t[cc + 1][r]; v[2] = t[cc + 2][r]; v[3] = t[cc + 3][r];
    *(u16x4*)(Wt + (size_t)(n0 + r) * D_DIM + k0 + cc) = v;
  }
}

// ---------------------------------------------------------------------------
// QKV GEMM + fused RoPE.  128x128 tile, BK=32, global_load_lds width-16.
// z=0,1 (Q,K): OPERAND-SWAPPED (A=W) -> C row = hd (in-lane), col = s.
//   Store: fragment-blocked [hd/4][s][4], u16x4 contiguous, lane-coalesced.
// z=2 (V): normal (A=X) -> C row = s (in-lane), col = hd.  RoPE via
//   shfl-pair; pack 4 consecutive s -> one u16x4 store into [s/4][hd][4].
// ---------------------------------------------------------------------------
__global__ __launch_bounds__(256) void qkv_gemm(const float* __restrict__ sin_t,
                                                const float* __restrict__ cos_t) {
  __shared__ __attribute__((aligned(16))) u16 lds_a[128 * 32];
  __shared__ __attribute__((aligned(16))) u16 lds_b[128 * 32];
  const int tid = threadIdx.x;
  const int wv = tid >> 6;
  const int lane = tid & 63;
  const int lrow = lane & 15;
  const int quad = lane >> 4;
  const int wr = wv >> 1, wc = wv & 1;
  const int m0 = blockIdx.x * 128;   // X rows (s-dim)
  const int n0 = blockIdx.y * 128;   // W out-features (h*64+hd)
  const int z = blockIdx.z;
  const bool vmode = (z == 2);
  const u16* Wz = g_wt + (size_t)z * (D_DIM * D_DIM);

  floatx4 acc[4][4] = {};

  const u16* gA = g_xb + (size_t)(m0 + wv * 32 + (lane >> 2)) * D_DIM + (lane & 3) * 8;
  const u16* gB = Wz   + (size_t)(n0 + wv * 32 + (lane >> 2)) * D_DIM + (lane & 3) * 8;
  u16* sA = &lds_a[(wv * 32) * 32];
  u16* sB = &lds_b[(wv * 32) * 32];

  // Q/K: A-port reads W (lds_b), B-port reads X (lds_a).  V: opposite.
  const u16* Aarr = vmode ? lds_a : lds_b;
  const u16* Barr = vmode ? lds_b : lds_a;

  for (int k0 = 0; k0 < D_DIM; k0 += 32) {
    __syncthreads();
    load_lds16(gA + k0, sA);
    load_lds16(gA + (size_t)16 * D_DIM + k0, sA + 512);
    load_lds16(gB + k0, sB);
    load_lds16(gB + (size_t)16 * D_DIM + k0, sB + 512);
    __syncthreads();
    u16x8 af[4], bfr[4];
#pragma unroll
    for (int mi = 0; mi < 4; ++mi)
      af[mi] = *(const u16x8*)&Aarr[(wr * 64 + mi * 16 + lrow) * 32 + quad * 8];
#pragma unroll
    for (int ni = 0; ni < 4; ++ni)
      bfr[ni] = *(const u16x8*)&Barr[(wc * 64 + ni * 16 + lrow) * 32 + quad * 8];
#pragma unroll
    for (int mi = 0; mi < 4; ++mi)
#pragma unroll
      for (int ni = 0; ni < 4; ++ni)
        acc[mi][ni] = __builtin_amdgcn_mfma_f32_16x16x32_bf16(
            asbf(af[mi]), asbf(bfr[ni]), acc[mi][ni], 0, 0, 0);
  }

  if (!vmode) {
    // Q/K: C row (quad*4+r) = feature (hd), col (lrow) = s
    const float qsc = (z == 0) ? 0.18033688011112042f : 1.0f; // 0.125*log2(e)
    u16* outz = g_qkv + (size_t)z * (BATCH * S_LEN * D_DIM);
#pragma unroll
    for (int mi = 0; mi < 4; ++mi) {
      const int nf0 = n0 + wr * 64 + mi * 16 + quad * 4;  // features nf0..nf0+3
      const int h = nf0 >> 6, hd0 = nf0 & 63, i00 = hd0 >> 1;
#pragma unroll
      for (int ni = 0; ni < 4; ++ni) {
        const int sg = m0 + wc * 64 + ni * 16 + lrow;
        const int b = sg >> 11, srow = sg & 2047;
        const float c0 = cos_t[(size_t)srow * 32 + i00];
        const float s0 = sin_t[(size_t)srow * 32 + i00];
        const float c1 = cos_t[(size_t)srow * 32 + i00 + 1];
        const float s1 = sin_t[(size_t)srow * 32 + i00 + 1];
        const float v0 = acc[mi][ni][0], v1 = acc[mi][ni][1];
        const float v2 = acc[mi][ni][2], v3 = acc[mi][ni][3];
        u16x4 ov;
        ov[0] = f2b((v0 * c0 - v1 * s0) * qsc);
        ov[1] = f2b((v1 * c0 + v0 * s0) * qsc);
        ov[2] = f2b((v2 * c1 - v3 * s1) * qsc);
        ov[3] = f2b((v3 * c1 + v2 * s1) * qsc);
        // fragment-blocked [hd/4][s][4]: contiguous u16x4, lanes stride 8B
        *(u16x4*)(outz + (size_t)(b * NH + h) * (S_LEN * HD) +
                  ((size_t)(hd0 >> 2) * S_LEN + srow) * 4) = ov;
      }
    }
  } else {
    // V: C row (quad*4+r) = s, col (lrow) = feature (hd)
    u16* outv = g_qkv + (size_t)2 * (BATCH * S_LEN * D_DIM);
#pragma unroll
    for (int mi = 0; mi < 4; ++mi) {
      const int s0g = m0 + wr * 64 + mi * 16 + quad * 4;  // s rows s0g..s0g+3
      const int b = s0g >> 11, sl = s0g & 2047;
#pragma unroll
      for (int ni = 0; ni < 4; ++ni) {
        const int nf = n0 + wc * 64 + ni * 16 + lrow;
        const int h = nf >> 6, hd = nf & 63, i0 = hd >> 1;
        const float sgn = (hd & 1) ? 1.f : -1.f;
        u16x4 ov;
#pragma unroll
        for (int r = 0; r < 4; ++r) {
          const int s = sl + r;
          const float c  = cos_t[(size_t)s * 32 + i0];
          const float sn = sin_t[(size_t)s * 32 + i0];
          const float v  = acc[mi][ni][r];
          const float vp = __shfl_xor(v, 1);
          ov[r] = f2b(v * c + sgn * sn * vp);
        }
        // fragment-blocked: offset = ((sl>>2)*HD + hd)*4  (sl % 4 == 0)
        *(u16x4*)(outv + (size_t)(b * NH + h) * (S_LEN * HD) +
                  ((size_t)(sl >> 2) * HD + hd) * 4) = ov;
      }
    }
  }
}

// ---------------------------------------------------------------------------
// Flash attention = round-5 structure (KVBLK=128, 32 q/wave, single barrier
// per tile), K/Q sourced from the new blocked [hd/4][s][4] layout:
//  - Q prologue: 2 x b64 per fragment (hd run crosses two j-chunks).
//  - K staging: per-j 1KB contiguous global runs -> wave-perfect coalescing;
//    LDS K layout [j][128][4] with pitch 520 u16 (j-step = 260 dw == 8 banks
//    per quad*2 -> kf b64 reads land 4 accesses/bank = minimum aliasing).
//  - kf = cat(b64 at j0, b64 at j0+1); fragment VALUES identical to round 5.
// Everything else (datapath, V path, epilogue) byte-identical to round 5.
// ---------------------------------------------------------------------------
#define VP 260   // LDS pitch (u16) per 4-row kv block of V
#define KP 520   // LDS pitch (u16) per j-chunk of K (512 data + 8 pad)
__global__ __launch_bounds__(256) void flash_attn(float* __restrict__ out) {
  __shared__ __attribute__((aligned(16))) u16 lds_k[2][16 * KP];   // 33.3 KB
  __shared__ __attribute__((aligned(16))) u16 lds_v[2][32 * VP];   // 33.3 KB
  const int bh = blockIdx.x;
  const int qt = blockIdx.y;
  const int b = bh >> 4, h = bh & 15;
  const int tid = threadIdx.x, wv = tid >> 6, lane = tid & 63;
  const int lrow = lane & 15, quad = lane >> 4;
  const u16* Qb = g_qkv + (size_t)bh * (S_LEN * HD);                      // blocked
  const u16* Kb = g_qkv + (size_t)(BATCH * NH + bh) * (S_LEN * HD);       // blocked
  const u16* Vb = g_qkv + (size_t)(2 * BATCH * NH + bh) * (S_LEN * HD);   // blocked
  const int q0 = qt * 128 + wv * 32;

  // Q fragments for this wave's 32 q rows (2 subtiles x 2 k-halves),
  // from blocked layout: hd = ks*32+quad*8+e -> j0 = ks*8+quad*2, j0+1
  u16x8 qf[2][2];
#pragma unroll
  for (int qb = 0; qb < 2; ++qb)
#pragma unroll
    for (int ks = 0; ks < 2; ++ks) {
      const int q = q0 + qb * 16 + lrow;
      const int j0 = ks * 8 + quad * 2;
      qf[qb][ks] = cat44(
          *(const u16x4*)(Qb + ((size_t)j0 * S_LEN + q) * 4),
          *(const u16x4*)(Qb + ((size_t)(j0 + 1) * S_LEN + q) * 4));
    }

  floatx4 oacc[2][4] = {};   // [qb][hb]: O[q=qb*16+quad*4+r][hd=hb*16+lrow]
  float l_part[2] = {};      // [qb]: l partial for q = qb*16+lrow (this quad)

  // prefetch tile 0 into registers
  // K: 1024 16B-chunks per tile; thread handles u = i*256+tid:
  //   j = u>>6, w = u&63;  global = Kb + j*8192 + t*512 + w*8;  lds = j*KP + w*8
  u16x8 kreg[4], vreg[4];
#pragma unroll
  for (int i = 0; i < 4; ++i) {
    const int u = i * 256 + tid, j = u >> 6, w = u & 63;
    kreg[i] = *(const u16x8*)(Kb + (size_t)j * (S_LEN * 4) + w * 8);
  }
#pragma unroll
  for (int c = 0; c < 4; ++c)
    vreg[c] = *(const u16x8*)(Vb + (size_t)c * 2048 + tid * 8);

  for (int t = 0; t < S_LEN / 128; ++t) {
    const int buf = t & 1;
#pragma unroll
    for (int i = 0; i < 4; ++i) {
      const int u = i * 256 + tid, j = u >> 6, w = u & 63;
      *(u16x8*)&lds_k[buf][j * KP + w * 8] = kreg[i];
    }
#pragma unroll
    for (int c = 0; c < 4; ++c) {
      const int off = c * 2048 + tid * 8;
      *(u16x8*)&lds_v[buf][(off >> 8) * VP + (off & 255)] = vreg[c];
    }
    __syncthreads();
    if (t + 1 < S_LEN / 128) {
#pragma unroll
      for (int i = 0; i < 4; ++i) {
        const int u = i * 256 + tid, j = u >> 6, w = u & 63;
        kreg[i] = *(const u16x8*)(Kb + (size_t)j * (S_LEN * 4) +
                                  (size_t)(t + 1) * 512 + w * 8);
      }
      const size_t vn = (size_t)(t + 1) * 128 * HD;
#pragma unroll
      for (int c = 0; c < 4; ++c)
        vreg[c] = *(const u16x8*)(Vb + vn + (size_t)c * 2048 + tid * 8);
    }

#pragma unroll
    for (int sub = 0; sub < 2; ++sub) {
      // K / V fragments for this 64-row sub-tile — shared by both q-subtiles
      u16x8 kf[4][2];
#pragma unroll
      for (int nb = 0; nb < 4; ++nb)
#pragma unroll
        for (int ks = 0; ks < 2; ++ks) {
          const int j0 = ks * 8 + quad * 2;
          const int ro = (sub * 64 + nb * 16 + lrow) * 4;
          kf[nb][ks] = cat44(
              *(const u16x4*)&lds_k[buf][j0 * KP + ro],
              *(const u16x4*)&lds_k[buf][(j0 + 1) * KP + ro]);
        }
      u16x4 vf[4][4];
#pragma unroll
      for (int nb = 0; nb < 4; ++nb)
#pragma unroll
        for (int hb = 0; hb < 4; ++hb)
          vf[nb][hb] = *(const u16x4*)&lds_v[buf][(sub * 16 + nb * 4 + quad) * VP +
                                                 (hb * 16 + lrow) * 4];

      // S^T = K Q^T for both q-subtiles (C: col = q = lrow, row = kv)
      floatx4 sacc[2][4];
      __builtin_amdgcn_s_setprio(1);
#pragma unroll
      for (int qb = 0; qb < 2; ++qb)
#pragma unroll
        for (int nb = 0; nb < 4; ++nb) {
          floatx4 s0 = {};
          s0 = __builtin_amdgcn_mfma_f32_16x16x32_bf16(
              asbf(kf[nb][0]), asbf(qf[qb][0]), s0, 0, 0, 0);
          sacc[qb][nb] = __builtin_amdgcn_mfma_f32_16x16x32_bf16(
              asbf(kf[nb][1]), asbf(qf[qb][1]), s0, 0, 0, 0);
        }
      __builtin_amdgcn_s_setprio(0);

      // P = exp2(S) in-lane; pack to bf16x4 (= PV K=16 A-fragment)
      s16x4 pa[2][4];
#pragma unroll
      for (int qb = 0; qb < 2; ++qb)
#pragma unroll
        for (int nb = 0; nb < 4; ++nb) {
          const float p0 = __builtin_amdgcn_exp2f(sacc[qb][nb][0]);
          const float p1 = __builtin_amdgcn_exp2f(sacc[qb][nb][1]);
          const float p2 = __builtin_amdgcn_exp2f(sacc[qb][nb][2]);
          const float p3 = __builtin_amdgcn_exp2f(sacc[qb][nb][3]);
          l_part[qb] += (p0 + p1) + (p2 + p3);
          uint2 pk;
          pk.x = __byte_perm(fbits(p0), fbits(p1), 0x7632);
          pk.y = __byte_perm(fbits(p2), fbits(p3), 0x7632);
          pa[qb][nb] = as4(pk);
        }

      // O += P V  (vf shared across qb)
      __builtin_amdgcn_s_setprio(1);
#pragma unroll
      for (int qb = 0; qb < 2; ++qb)
#pragma unroll
        for (int nb = 0; nb < 4; ++nb)
#pragma unroll
          for (int hb = 0; hb < 4; ++hb)
            oacc[qb][hb] = __builtin_amdgcn_mfma_f32_16x16x16bf16_1k(
                pa[qb][nb], as4u(vf[nb][hb]), oacc[qb][hb], 0, 0, 0);
      __builtin_amdgcn_s_setprio(0);
    }
    // single barrier per tile: next iter writes buf^1; a wave reaches that
    // write only after passing barrier(t), which requires all waves to have
    // finished iter t-1 (whose reads were the last touch of buf^1). ✓
  }

  // epilogue: per-wave (disjoint q rows).  l: combine quads; then scale.
#pragma unroll
  for (int qb = 0; qb < 2; ++qb) {
    float l = l_part[qb];
    l += __shfl_xor(l, 16);
    l += __shfl_xor(l, 32);
    float linv[4];
#pragma unroll
    for (int r = 0; r < 4; ++r)
      linv[r] = 1.f / __shfl(l, quad * 4 + r);
#pragma unroll
    for (int hb = 0; hb < 4; ++hb) {
      const int hd = hb * 16 + lrow;
#pragma unroll
      for (int r = 0; r < 4; ++r) {
        const int q = q0 + qb * 16 + quad * 4 + r;
        out[((size_t)(b * S_LEN) + q) * D_DIM + h * HD + hd] =
            oacc[qb][hb][r] * linv[r];
      }
    }
  }
}

// ---------------------------------------------------------------------------
extern "C" void kernel_launch(void* const* d_in, const int* in_sizes, int n_in,
                              void* d_out, int out_size, void* d_ws, size_t ws_size,
                              hipStream_t stream) {
  const float* X = (const float*)d_in[0];
  const float* sin_t = (const float*)d_in[4];
  const float* cos_t = (const float*)d_in[5];

  prep<<<dim3(256, 4), 256, 0, stream>>>(X, (const float*)d_in[1],
                                         (const float*)d_in[2],
                                         (const float*)d_in[3]);

  qkv_gemm<<<dim3(32, 8, 3), 256, 0, stream>>>(sin_t, cos_t);

  flash_attn<<<dim3(32, 16), 256, 0, stream>>>((float*)d_out);
}

// Round 8
// 180.022 us; speedup vs baseline: 1.0396x; 1.0396x over previous
//
#include <hip/hip_runtime.h>

typedef unsigned short u16;
typedef unsigned short u16x8 __attribute__((ext_vector_type(8)));
typedef unsigned short u16x4 __attribute__((ext_vector_type(4)));
typedef short s16x4 __attribute__((ext_vector_type(4)));
typedef __bf16 bf16x8_t __attribute__((ext_vector_type(8)));
typedef float floatx4 __attribute__((ext_vector_type(4)));

#define BATCH 2
#define S_LEN 2048
#define D_DIM 1024
#define NH    16
#define HD    64

__device__ __forceinline__ u16 f2b(float f) {   // RNE, finite only
  union { float f; unsigned int i; } c; c.f = f;
  const unsigned int i = c.i;
  return (u16)((i + 0x7FFFu + ((i >> 16) & 1u)) >> 16);
}
__device__ __forceinline__ unsigned int fbits(float f) {
  union { float f; unsigned int i; } c; c.f = f; return c.i;
}
__device__ __forceinline__ bf16x8_t asbf(u16x8 v) {
  union { u16x8 u; bf16x8_t b; } c; c.u = v; return c.b;
}
__device__ __forceinline__ s16x4 as4(uint2 v) {
  union { uint2 u; s16x4 s; } c; c.u = v; return c.s;
}
__device__ __forceinline__ s16x4 as4u(u16x4 v) {
  union { u16x4 u; s16x4 s; } c; c.u = v; return c.s;
}
__device__ __forceinline__ void load_lds16(const u16* g, u16* l) {
  __builtin_amdgcn_global_load_lds(
      (const __attribute__((address_space(1))) void*)g,
      (__attribute__((address_space(3))) void*)l, 16, 0, 0);
}

// Scratch in device globals, fully rewritten every call (graph-replay safe).
__device__ __attribute__((aligned(256))) u16 g_xb[(size_t)BATCH * S_LEN * D_DIM];   // 8 MB
__device__ __attribute__((aligned(256))) u16 g_wt[3u * D_DIM * D_DIM];              // 6 MB
// Q (pre-scaled by 0.125*log2e), K: [bh][s][hd].
// V: fragment-blocked [bh][s/4][hd][4]  (value V(s,hd) at ((s>>2)*64+hd)*4+(s&3))
__device__ __attribute__((aligned(256))) u16 g_qkv[3u * BATCH * S_LEN * D_DIM];     // 25 MB

// ---------------------------------------------------------------------------
// Fused prep: blockIdx.y = 0..2 -> transpose+convert W[y]; y = 3 -> convert X.
// ---------------------------------------------------------------------------
__global__ __launch_bounds__(256) void prep(const float* __restrict__ X,
                                            const float* __restrict__ Wq,
                                            const float* __restrict__ Wk,
                                            const float* __restrict__ Wv) {
  const int tid = threadIdx.x;
  const int z = blockIdx.y;
  if (z == 3) {
#pragma unroll
    for (int c = 0; c < 8; ++c) {
      const size_t i = (((size_t)c * 256 + blockIdx.x) * 256 + tid) * 8;
      floatx4 a = *(const floatx4*)(X + i);
      floatx4 b = *(const floatx4*)(X + i + 4);
      u16x8 o;
#pragma unroll
      for (int j = 0; j < 4; ++j) { o[j] = f2b(a[j]); o[4 + j] = f2b(b[j]); }
      *(u16x8*)(g_xb + i) = o;
    }
    return;
  }
  __shared__ u16 t[64][65];
  const float* W = (z == 0) ? Wq : (z == 1) ? Wk : Wv;
  u16* Wt = g_wt + (size_t)z * D_DIM * D_DIM;
  const int k0 = (blockIdx.x & 15) * 64;
  const int n0 = (blockIdx.x >> 4) * 64;
  const int rr = tid >> 4;
  const int cc = (tid & 15) * 4;
#pragma unroll
  for (int i = 0; i < 4; ++i) {
    const int r = rr + i * 16;
    floatx4 v = *(const floatx4*)(W + (size_t)(k0 + r) * D_DIM + n0 + cc);
    t[r][cc] = f2b(v[0]); t[r][cc + 1] = f2b(v[1]);
    t[r][cc + 2] = f2b(v[2]); t[r][cc + 3] = f2b(v[3]);
  }
  __syncthreads();
#pragma unroll
  for (int i = 0; i < 4; ++i) {
    const int r = rr + i * 16;
    u16x4 v;
    v[0] = t[cc][r]; v[1] = t[cc + 1][r]; v[2] = t[cc + 2][r]; v[3] = t[cc + 3][r];
    *(u16x4*)(Wt + (size_t)(n0 + r) * D_DIM + k0 + cc) = v;
  }
}

// ---------------------------------------------------------------------------
// QKV GEMM + fused RoPE.  128x128 tile, BK=32, global_load_lds width-16.
// z=0,1 (Q,K): OPERAND-SWAPPED (A=W) -> C row = hd (in-lane), col = s.
// z=2 (V): normal (A=X) -> C row = s (in-lane), col = hd.  RoPE via
//   shfl-pair; pack 4 consecutive s -> one u16x4 store into the
//   fragment-blocked layout [s/4][hd][4] (contiguous, coalesced).
// ---------------------------------------------------------------------------
__global__ __launch_bounds__(256) void qkv_gemm(const float* __restrict__ sin_t,
                                                const float* __restrict__ cos_t) {
  __shared__ __attribute__((aligned(16))) u16 lds_a[128 * 32];
  __shared__ __attribute__((aligned(16))) u16 lds_b[128 * 32];
  const int tid = threadIdx.x;
  const int wv = tid >> 6;
  const int lane = tid & 63;
  const int lrow = lane & 15;
  const int quad = lane >> 4;
  const int wr = wv >> 1, wc = wv & 1;
  const int m0 = blockIdx.x * 128;   // X rows (s-dim)
  const int n0 = blockIdx.y * 128;   // W out-features (h*64+hd)
  const int z = blockIdx.z;
  const bool vmode = (z == 2);
  const u16* Wz = g_wt + (size_t)z * (D_DIM * D_DIM);

  floatx4 acc[4][4] = {};

  const u16* gA = g_xb + (size_t)(m0 + wv * 32 + (lane >> 2)) * D_DIM + (lane & 3) * 8;
  const u16* gB = Wz   + (size_t)(n0 + wv * 32 + (lane >> 2)) * D_DIM + (lane & 3) * 8;
  u16* sA = &lds_a[(wv * 32) * 32];
  u16* sB = &lds_b[(wv * 32) * 32];

  // Q/K: A-port reads W (lds_b), B-port reads X (lds_a).  V: opposite.
  const u16* Aarr = vmode ? lds_a : lds_b;
  const u16* Barr = vmode ? lds_b : lds_a;

  for (int k0 = 0; k0 < D_DIM; k0 += 32) {
    __syncthreads();
    load_lds16(gA + k0, sA);
    load_lds16(gA + (size_t)16 * D_DIM + k0, sA + 512);
    load_lds16(gB + k0, sB);
    load_lds16(gB + (size_t)16 * D_DIM + k0, sB + 512);
    __syncthreads();
    u16x8 af[4], bfr[4];
#pragma unroll
    for (int mi = 0; mi < 4; ++mi)
      af[mi] = *(const u16x8*)&Aarr[(wr * 64 + mi * 16 + lrow) * 32 + quad * 8];
#pragma unroll
    for (int ni = 0; ni < 4; ++ni)
      bfr[ni] = *(const u16x8*)&Barr[(wc * 64 + ni * 16 + lrow) * 32 + quad * 8];
#pragma unroll
    for (int mi = 0; mi < 4; ++mi)
#pragma unroll
      for (int ni = 0; ni < 4; ++ni)
        acc[mi][ni] = __builtin_amdgcn_mfma_f32_16x16x32_bf16(
            asbf(af[mi]), asbf(bfr[ni]), acc[mi][ni], 0, 0, 0);
  }

  if (!vmode) {
    // Q/K: C row (quad*4+r) = feature (hd), col (lrow) = s
    const float qsc = (z == 0) ? 0.18033688011112042f : 1.0f; // 0.125*log2(e)
    u16* outz = g_qkv + (size_t)z * (BATCH * S_LEN * D_DIM);
#pragma unroll
    for (int mi = 0; mi < 4; ++mi) {
      const int nf0 = n0 + wr * 64 + mi * 16 + quad * 4;  // features nf0..nf0+3
      const int h = nf0 >> 6, hd0 = nf0 & 63, i00 = hd0 >> 1;
#pragma unroll
      for (int ni = 0; ni < 4; ++ni) {
        const int sg = m0 + wc * 64 + ni * 16 + lrow;
        const int b = sg >> 11, srow = sg & 2047;
        const float c0 = cos_t[(size_t)srow * 32 + i00];
        const float s0 = sin_t[(size_t)srow * 32 + i00];
        const float c1 = cos_t[(size_t)srow * 32 + i00 + 1];
        const float s1 = sin_t[(size_t)srow * 32 + i00 + 1];
        const float v0 = acc[mi][ni][0], v1 = acc[mi][ni][1];
        const float v2 = acc[mi][ni][2], v3 = acc[mi][ni][3];
        u16x4 ov;
        ov[0] = f2b((v0 * c0 - v1 * s0) * qsc);
        ov[1] = f2b((v1 * c0 + v0 * s0) * qsc);
        ov[2] = f2b((v2 * c1 - v3 * s1) * qsc);
        ov[3] = f2b((v3 * c1 + v2 * s1) * qsc);
        *(u16x4*)(outz + ((size_t)(b * NH + h) * S_LEN + srow) * HD + hd0) = ov;
      }
    }
  } else {
    // V: C row (quad*4+r) = s, col (lrow) = feature (hd)
    u16* outv = g_qkv + (size_t)2 * (BATCH * S_LEN * D_DIM);
#pragma unroll
    for (int mi = 0; mi < 4; ++mi) {
      const int s0g = m0 + wr * 64 + mi * 16 + quad * 4;  // s rows s0g..s0g+3
      const int b = s0g >> 11, sl = s0g & 2047;
#pragma unroll
      for (int ni = 0; ni < 4; ++ni) {
        const int nf = n0 + wc * 64 + ni * 16 + lrow;
        const int h = nf >> 6, hd = nf & 63, i0 = hd >> 1;
        const float sgn = (hd & 1) ? 1.f : -1.f;
        u16x4 ov;
#pragma unroll
        for (int r = 0; r < 4; ++r) {
          const int s = sl + r;
          const float c  = cos_t[(size_t)s * 32 + i0];
          const float sn = sin_t[(size_t)s * 32 + i0];
          const float v  = acc[mi][ni][r];
          const float vp = __shfl_xor(v, 1);
          ov[r] = f2b(v * c + sgn * sn * vp);
        }
        // fragment-blocked: offset = ((sl>>2)*HD + hd)*4  (sl % 4 == 0)
        *(u16x4*)(outv + (size_t)(b * NH + h) * (S_LEN * HD) +
                  ((size_t)(sl >> 2) * HD + hd) * 4) = ov;
      }
    }
  }
}

// ---------------------------------------------------------------------------
// Flash attention = round-5 structure (KVBLK=128, 32 q/wave, q-split waves,
// single barrier per tile, row-major K staging [128][72], V blocked [32][VP])
// + ONE change: the softmax denominator l is computed on the MFMA pipe via a
// ones-column K=16 MFMA (l4[qb] += P_frag x ONES), replacing 64 VALU adds
// per sub-tile and the epilogue cross-quad shuffles.  The ones-MFMA C-layout
// puts l[q] at l4[qb][r] for q = qb*16 + quad*4 + r (replicated across lrow),
// exactly matching oacc's row mapping -> linv[r] = 1/l4[qb][r] directly.
// ---------------------------------------------------------------------------
#define VP 260   // LDS pitch (u16) per 4-row kv block of V
__global__ __launch_bounds__(256) void flash_attn(float* __restrict__ out) {
  __shared__ __attribute__((aligned(16))) u16 lds_k[2][128 * 72];  // 36.9 KB
  __shared__ __attribute__((aligned(16))) u16 lds_v[2][32 * VP];   // 33.3 KB
  const int bh = blockIdx.x;
  const int qt = blockIdx.y;
  const int b = bh >> 4, h = bh & 15;
  const int tid = threadIdx.x, wv = tid >> 6, lane = tid & 63;
  const int lrow = lane & 15, quad = lane >> 4;
  const u16* Qb = g_qkv + (size_t)bh * (S_LEN * HD);
  const u16* Kb = g_qkv + (size_t)(BATCH * NH + bh) * (S_LEN * HD);
  const u16* Vb = g_qkv + (size_t)(2 * BATCH * NH + bh) * (S_LEN * HD); // blocked
  const int q0 = qt * 128 + wv * 32;

  // Q fragments for this wave's 32 q rows (2 subtiles x 2 k-halves)
  u16x8 qf[2][2];
#pragma unroll
  for (int qb = 0; qb < 2; ++qb)
#pragma unroll
    for (int ks = 0; ks < 2; ++ks)
      qf[qb][ks] = *(const u16x8*)(Qb + (size_t)(q0 + qb * 16 + lrow) * HD +
                                   ks * 32 + quad * 8);

  floatx4 oacc[2][4] = {};   // [qb][hb]: O[q=qb*16+quad*4+r][hd=hb*16+lrow]
  floatx4 l4[2] = {};        // [qb][r]:  l[q=qb*16+quad*4+r] (all lrow equal)
  const u16x4 ones = {0x3F80u, 0x3F80u, 0x3F80u, 0x3F80u};  // bf16 1.0 x4

  // K staging: row = tid>>1 (0..127), 64B per thread in 4 x 16B
  const int krow = tid >> 1;
  const int kcol = (tid & 1) * 32;

  // prefetch tile 0 into registers
  u16x8 kreg[4], vreg[4];
#pragma unroll
  for (int i = 0; i < 4; ++i)
    kreg[i] = *(const u16x8*)(Kb + (size_t)krow * HD + kcol + i * 8);
#pragma unroll
  for (int c = 0; c < 4; ++c)
    vreg[c] = *(const u16x8*)(Vb + (size_t)c * 2048 + tid * 8);

  for (int t = 0; t < S_LEN / 128; ++t) {
    const int buf = t & 1;
#pragma unroll
    for (int i = 0; i < 4; ++i)
      *(u16x8*)&lds_k[buf][krow * 72 + kcol + i * 8] = kreg[i];
#pragma unroll
    for (int c = 0; c < 4; ++c) {
      const int off = c * 2048 + tid * 8;
      *(u16x8*)&lds_v[buf][(off >> 8) * VP + (off & 255)] = vreg[c];
    }
    __syncthreads();
    if (t + 1 < S_LEN / 128) {
      const size_t kn = (size_t)(t + 1) * 128 * HD;
#pragma unroll
      for (int i = 0; i < 4; ++i)
        kreg[i] = *(const u16x8*)(Kb + kn + (size_t)krow * HD + kcol + i * 8);
#pragma unroll
      for (int c = 0; c < 4; ++c)
        vreg[c] = *(const u16x8*)(Vb + kn + (size_t)c * 2048 + tid * 8);
    }

#pragma unroll
    for (int sub = 0; sub < 2; ++sub) {
      // K / V fragments for this 64-row sub-tile — shared by both q-subtiles
      u16x8 kf[4][2];
#pragma unroll
      for (int nb = 0; nb < 4; ++nb)
#pragma unroll
        for (int ks = 0; ks < 2; ++ks)
          kf[nb][ks] = *(const u16x8*)&lds_k[buf][(sub * 64 + nb * 16 + lrow) * 72 +
                                                 ks * 32 + quad * 8];
      u16x4 vf[4][4];
#pragma unroll
      for (int nb = 0; nb < 4; ++nb)
#pragma unroll
        for (int hb = 0; hb < 4; ++hb)
          vf[nb][hb] = *(const u16x4*)&lds_v[buf][(sub * 16 + nb * 4 + quad) * VP +
                                                 (hb * 16 + lrow) * 4];

      // S^T = K Q^T for both q-subtiles (C: col = q = lrow, row = kv)
      floatx4 sacc[2][4];
      __builtin_amdgcn_s_setprio(1);
#pragma unroll
      for (int qb = 0; qb < 2; ++qb)
#pragma unroll
        for (int nb = 0; nb < 4; ++nb) {
          floatx4 s0 = {};
          s0 = __builtin_amdgcn_mfma_f32_16x16x32_bf16(
              asbf(kf[nb][0]), asbf(qf[qb][0]), s0, 0, 0, 0);
          sacc[qb][nb] = __builtin_amdgcn_mfma_f32_16x16x32_bf16(
              asbf(kf[nb][1]), asbf(qf[qb][1]), s0, 0, 0, 0);
        }
      __builtin_amdgcn_s_setprio(0);

      // P = exp2(S) in-lane; pack to bf16x4 (= PV K=16 A-fragment)
      s16x4 pa[2][4];
#pragma unroll
      for (int qb = 0; qb < 2; ++qb)
#pragma unroll
        for (int nb = 0; nb < 4; ++nb) {
          const float p0 = __builtin_amdgcn_exp2f(sacc[qb][nb][0]);
          const float p1 = __builtin_amdgcn_exp2f(sacc[qb][nb][1]);
          const float p2 = __builtin_amdgcn_exp2f(sacc[qb][nb][2]);
          const float p3 = __builtin_amdgcn_exp2f(sacc[qb][nb][3]);
          uint2 pk;
          pk.x = __byte_perm(fbits(p0), fbits(p1), 0x7632);
          pk.y = __byte_perm(fbits(p2), fbits(p3), 0x7632);
          pa[qb][nb] = as4(pk);
        }

      // O += P V ; l += P * ones   (all on the MFMA pipe; vf shared across qb)
      __builtin_amdgcn_s_setprio(1);
#pragma unroll
      for (int qb = 0; qb < 2; ++qb)
#pragma unroll
        for (int nb = 0; nb < 4; ++nb) {
#pragma unroll
          for (int hb = 0; hb < 4; ++hb)
            oacc[qb][hb] = __builtin_amdgcn_mfma_f32_16x16x16bf16_1k(
                pa[qb][nb], as4u(vf[nb][hb]), oacc[qb][hb], 0, 0, 0);
          l4[qb] = __builtin_amdgcn_mfma_f32_16x16x16bf16_1k(
              pa[qb][nb], as4u(ones), l4[qb], 0, 0, 0);
        }
      __builtin_amdgcn_s_setprio(0);
    }
    // single barrier per tile: next iter writes buf^1; a wave reaches that
    // write only after passing barrier(t), which requires all waves to have
    // finished iter t-1 (whose reads were the last touch of buf^1). ✓
  }

  // epilogue: per-wave (disjoint q rows); l4[qb][r] already holds l[q] for
  // q = q0 + qb*16 + quad*4 + r (no cross-lane reduction needed).
#pragma unroll
  for (int qb = 0; qb < 2; ++qb) {
    float linv[4];
#pragma unroll
    for (int r = 0; r < 4; ++r)
      linv[r] = 1.f / l4[qb][r];
#pragma unroll
    for (int hb = 0; hb < 4; ++hb) {
      const int hd = hb * 16 + lrow;
#pragma unroll
      for (int r = 0; r < 4; ++r) {
        const int q = q0 + qb * 16 + quad * 4 + r;
        out[((size_t)(b * S_LEN) + q) * D_DIM + h * HD + hd] =
            oacc[qb][hb][r] * linv[r];
      }
    }
  }
}

// ---------------------------------------------------------------------------
extern "C" void kernel_launch(void* const* d_in, const int* in_sizes, int n_in,
                              void* d_out, int out_size, void* d_ws, size_t ws_size,
                              hipStream_t stream) {
  const float* X = (const float*)d_in[0];
  const float* sin_t = (const float*)d_in[4];
  const float* cos_t = (const float*)d_in[5];

  prep<<<dim3(256, 4), 256, 0, stream>>>(X, (const float*)d_in[1],
                                         (const float*)d_in[2],
                                         (const float*)d_in[3]);

  qkv_gemm<<<dim3(32, 8, 3), 256, 0, stream>>>(sin_t, cos_t);

  flash_attn<<<dim3(32, 16), 256, 0, stream>>>((float*)d_out);
}